// Round 5
// baseline (118.295 us; speedup 1.0000x reference)
//
#include <hip/hip_runtime.h>

#define BOX    256
#define NCLS   2
#define BATCH  2
#define NPTS   262144                    // 2^18
#define VOL    (BOX * BOX * BOX)
#define NPTOT  (BATCH * NPTS)            // 524288 points
#define NGRP   256                       // coarse groups: (b<<7)|(bz>>1), 2 planes each
#define GCAP   3584                      // records/group capacity (mean 2048, +34 sigma)
#define NFINE  512                       // fine bins per group: (bz&1)<<8 | by
#define NBINS  (NGRP * NFINE)            // 131072 = (b, bz, by)
#define L1PTS  2048                      // points per L1 block
#define L1BLK  (NPTOT / L1PTS)           // 256
#define RY     16                        // rows per region tile
#define NREG   (BATCH * BOX * (BOX / RY))// 8192 region blocks

// ---------------------------------------------------------------------------
// Pass 0: zero group cursors + overflow counter (2 KB)
// ---------------------------------------------------------------------------
__global__ __launch_bounds__(512) void k_zero(unsigned* __restrict__ p)
{
    p[threadIdx.x] = 0u;   // covers gcur[256] + ovfcnt (+pad) = 512 u32
}

// ---------------------------------------------------------------------------
// Level 1: LDS-aggregated coarse sort into 256 (b, bz>>1) groups.
// Record (16B): x = ix(8) | qx15(<<8) | (bz&1)(<<23) | by(<<24)
//               y = qy16 | qz16<<16 ; z = v0 ; w = v1
// Copy-out is bucket-run contiguous (mean 8 recs = 128B) -> ~4x fewer
// scattered store transactions; global atomics 256/block -> 8x fewer.
// ---------------------------------------------------------------------------
__global__ __launch_bounds__(256) void k_l1(const float* __restrict__ pts,
                                            const float* __restrict__ vals,
                                            unsigned* __restrict__ gcur,
                                            uint4* __restrict__ rec1,
                                            uint4* __restrict__ ovf4,
                                            unsigned* __restrict__ ovfbin,
                                            unsigned* __restrict__ ovfcnt)
{
    __shared__ unsigned hist[256];   // counts -> inclusive scan
    __shared__ unsigned excl[256];
    __shared__ unsigned cur[256];
    __shared__ unsigned gbase[256];
    __shared__ uint4 stag[L1PTS];    // 32 KB staging

    const int t = threadIdx.x;
    hist[t] = 0;
    __syncthreads();

    uint4 rec[8];
    unsigned bkt[8];
    const int base = blockIdx.x * L1PTS;
    #pragma unroll
    for (int k = 0; k < 8; ++k) {
        const int gp = base + k * 256 + t;
        const int b = gp >> 18;
        const int n = gp & (NPTS - 1);
        const float* pp = pts + (size_t)gp * 3;
        const float px = (pp[0] + 0.5f) * 256.0f;
        const float py = (pp[1] + 0.5f) * 256.0f;
        const float pz = (pp[2] + 0.5f) * 256.0f;
        const float fx = floorf(px), fy = floorf(py), fz = floorf(pz);
        const int ix = (int)fx, by = (int)fy, bz = (int)fz;
        const unsigned qx = (unsigned)((px - fx) * 32768.0f);   // 15-bit
        const unsigned qy = (unsigned)((py - fy) * 65536.0f);   // 16-bit
        const unsigned qz = (unsigned)((pz - fz) * 65536.0f);   // 16-bit
        const float v0 = vals[(size_t)(b * 2) * NPTS + n];
        const float v1 = vals[(size_t)(b * 2 + 1) * NPTS + n];
        rec[k].x = (unsigned)ix | (qx << 8) | ((unsigned)(bz & 1) << 23)
                 | ((unsigned)by << 24);
        rec[k].y = (qy & 0xffffu) | (qz << 16);
        rec[k].z = __float_as_uint(v0);
        rec[k].w = __float_as_uint(v1);
        bkt[k] = ((unsigned)b << 7) | ((unsigned)bz >> 1);
        atomicAdd(&hist[bkt[k]], 1u);
    }
    __syncthreads();

    // inclusive Hillis-Steele scan of hist (in place, 8 steps)
    const unsigned own = hist[t];
    for (int off = 1; off < 256; off <<= 1) {
        unsigned v = 0;
        if (t >= off) v = hist[t - off];
        __syncthreads();
        hist[t] += v;
        __syncthreads();
    }
    const unsigned incl = hist[t];
    const unsigned ex = incl - own;
    excl[t] = ex;
    cur[t] = ex;
    if (own) gbase[t] = atomicAdd(&gcur[t], own);
    __syncthreads();

    // stage into bucket-sorted LDS order
    #pragma unroll
    for (int k = 0; k < 8; ++k) {
        const unsigned s = atomicAdd(&cur[bkt[k]], 1u);
        stag[s] = rec[k];
    }
    __syncthreads();   // cur[] now == inclusive counts

    // copy out: consecutive s -> consecutive global within each bucket run
    for (int s = t; s < L1PTS; s += 256) {
        int lo = 0, hi = 255;                 // smallest j with cur[j] > s
        while (lo < hi) {
            const int mid = (lo + hi) >> 1;
            if (cur[mid] > (unsigned)s) hi = mid; else lo = mid + 1;
        }
        const unsigned rel = s - excl[lo];
        const unsigned gaddr = gbase[lo] + rel;
        const uint4 r = stag[s];
        if (gaddr < GCAP) {
            rec1[(size_t)lo * GCAP + gaddr] = r;
        } else {
            const unsigned o = atomicAdd(ovfcnt, 1u);
            const unsigned zl = (r.x >> 23) & 1u;
            const unsigned by = r.x >> 24;
            ovf4[o] = r;
            ovfbin[o] = ((unsigned)lo << 9) | (zl << 8) | by;  // == (b,bz,by)
        }
    }
}

// ---------------------------------------------------------------------------
// Level 2: one block per group. Exact LDS counting-sort by (bz&1, by) into
// 512 fine bins; coalesced write-back + per-bin (start,count) tables.
// ---------------------------------------------------------------------------
__global__ __launch_bounds__(512) void k_l2(const uint4* __restrict__ rec1,
                                            const unsigned* __restrict__ gcur,
                                            uint4* __restrict__ rec2,
                                            unsigned* __restrict__ binStart,
                                            unsigned* __restrict__ binCnt)
{
    __shared__ unsigned hist[NFINE];
    __shared__ unsigned excl[NFINE];
    __shared__ unsigned cur[NFINE];
    __shared__ uint4 stag[GCAP];         // 56 KB

    const int t = threadIdx.x;
    const int g = blockIdx.x;
    hist[t] = 0;
    __syncthreads();

    unsigned cnt = gcur[g];
    if (cnt > GCAP) cnt = GCAP;          // excess already diverted to ovf by L1

    uint4 rec[7];
    unsigned fk[7];
    #pragma unroll
    for (int k = 0; k < 7; ++k) {        // GCAP/512 = 7
        const int s = t + k * 512;
        if (s < (int)cnt) {
            const uint4 r = rec1[(size_t)g * GCAP + s];
            const unsigned key = (((r.x >> 23) & 1u) << 8) | (r.x >> 24);
            rec[k] = r; fk[k] = key;
            atomicAdd(&hist[key], 1u);
        }
    }
    __syncthreads();

    const unsigned own = hist[t];
    for (int off = 1; off < 512; off <<= 1) {
        unsigned v = 0;
        if (t >= off) v = hist[t - off];
        __syncthreads();
        hist[t] += v;
        __syncthreads();
    }
    const unsigned incl = hist[t];
    const unsigned ex = incl - own;
    excl[t] = ex;
    cur[t] = ex;
    binStart[(g << 9) + t] = (unsigned)(g * GCAP) + ex;   // absolute index
    binCnt[(g << 9) + t] = own;
    __syncthreads();

    #pragma unroll
    for (int k = 0; k < 7; ++k) {
        const int s = t + k * 512;
        if (s < (int)cnt) {
            const unsigned sl = atomicAdd(&cur[fk[k]], 1u);
            stag[sl] = rec[k];
        }
    }
    __syncthreads();

    for (int s = t; s < (int)cnt; s += 512)               // coalesced
        rec2[(size_t)g * GCAP + s] = stag[s];
}

// ---------------------------------------------------------------------------
// Region pass: one block per (b, plane P, y-tile T). Records for each source
// plane are ONE contiguous range in rec2 (consecutive y-bins) -> coalesced
// gather, no per-record bin search. LDS-atomic accumulate, coalesced store.
// ---------------------------------------------------------------------------
__global__ __launch_bounds__(512) void k_region(const uint4* __restrict__ rec2,
                                                const unsigned* __restrict__ binStart,
                                                const unsigned* __restrict__ binCnt,
                                                const uint4* __restrict__ ovf4,
                                                const unsigned* __restrict__ ovfbin,
                                                const unsigned* __restrict__ ovfcnt,
                                                float* __restrict__ out)
{
    __shared__ float acc[NCLS * RY * BOX];   // 32 KB
    __shared__ unsigned meta[4];

    const int t = threadIdx.x;
    const int bid = blockIdx.x;
    const int b = bid >> 12;
    const int P = (bid >> 4) & 255;
    const int T = bid & 15;

    {
        float4* a4 = (float4*)acc;
        #pragma unroll
        for (int i = 0; i < 4; ++i)
            a4[i * 512 + t] = make_float4(0.f, 0.f, 0.f, 0.f);
    }
    if (t < 2) {
        const int zsrc = P - 1 + t;
        unsigned s = 0, e = 0;
        if (zsrc >= 0) {
            int ylo = 16 * T - 1; if (ylo < 0) ylo = 0;
            const int yhi = 16 * T + 15;
            const unsigned fb_lo = ((unsigned)b << 16) | ((unsigned)zsrc << 8) | (unsigned)ylo;
            const unsigned fb_hi = ((unsigned)b << 16) | ((unsigned)zsrc << 8) | (unsigned)yhi;
            s = binStart[fb_lo];
            e = binStart[fb_hi] + binCnt[fb_hi];
        }
        meta[2 * t] = s; meta[2 * t + 1] = e;
    }
    __syncthreads();

    const unsigned s1 = meta[0], e1 = meta[1], s2 = meta[2], e2 = meta[3];
    const int n1 = (int)(e1 - s1), n2 = (int)(e2 - s2), n = n1 + n2;

    for (int r = t; r < n; r += 512) {
        const int inP = (r >= n1);       // 1: record plane == P, 0: plane P-1
        const unsigned idx = inP ? (s2 + (unsigned)(r - n1)) : (s1 + (unsigned)r);
        const uint4 q = rec2[idx];
        const int ix = (int)(q.x & 255u);
        const float rx = (float)((q.x >> 8) & 0x7fffu) * (1.0f / 32768.0f);
        const int by = (int)(q.x >> 24);
        const float ry = (float)(q.y & 0xffffu) * (1.0f / 65536.0f);
        const float rz = (float)(q.y >> 16) * (1.0f / 65536.0f);
        const float v0 = __uint_as_float(q.z);
        const float v1 = __uint_as_float(q.w);
        const float wz = inP ? (1.0f - rz) : rz;
        const int yy0 = by - 16 * T;

        #pragma unroll
        for (int dy = 0; dy < 2; ++dy) {
            const int yy = yy0 + dy;
            if ((unsigned)yy < RY) {
                const float wzy = wz * (dy ? ry : 1.0f - ry);
                #pragma unroll
                for (int dx = 0; dx < 2; ++dx) {
                    const int x = ix + dx;
                    if (x < BOX) {
                        const float w = wzy * (dx ? rx : 1.0f - rx);
                        const int li = yy * BOX + x;
                        atomicAdd(&acc[li], w * v0);
                        atomicAdd(&acc[RY * BOX + li], w * v1);
                    }
                }
            }
        }
    }

    // overflow records (empty for this input; correctness path)
    const int oc = (int)*ovfcnt;
    for (int r = t; r < oc; r += 512) {
        const unsigned fb = ovfbin[r];
        if ((int)(fb >> 16) != b) continue;
        const int bz = (int)((fb >> 8) & 255u);
        if (bz != P && bz != P - 1) continue;
        const int by = (int)(fb & 255u);
        const int yy0 = by - 16 * T;
        if (yy0 < -1 || yy0 > RY - 1) continue;
        const uint4 q = ovf4[r];
        const int ix = (int)(q.x & 255u);
        const float rx = (float)((q.x >> 8) & 0x7fffu) * (1.0f / 32768.0f);
        const float ry = (float)(q.y & 0xffffu) * (1.0f / 65536.0f);
        const float rz = (float)(q.y >> 16) * (1.0f / 65536.0f);
        const float wz = (bz == P) ? (1.0f - rz) : rz;
        for (int dy = 0; dy < 2; ++dy) {
            const int yy = yy0 + dy;
            if ((unsigned)yy < RY) {
                const float wzy = wz * (dy ? ry : 1.0f - ry);
                for (int dx = 0; dx < 2; ++dx) {
                    const int x = ix + dx;
                    if (x < BOX) {
                        const float w = wzy * (dx ? rx : 1.0f - rx);
                        const int li = yy * BOX + x;
                        atomicAdd(&acc[li], w * __uint_as_float(q.z));
                        atomicAdd(&acc[RY * BOX + li], w * __uint_as_float(q.w));
                    }
                }
            }
        }
    }
    __syncthreads();

    // stream tile out: [b][c][P][16T..16T+15][:] — coalesced float4
    #pragma unroll
    for (int c = 0; c < NCLS; ++c) {
        const size_t o4base = (size_t)((b * NCLS + c) * BOX + P) * (BOX * BOX / 4)
                              + (size_t)T * (RY * BOX / 4);
        float4* o4 = (float4*)out;
        const float4* a4 = (const float4*)(acc + c * RY * BOX);
        #pragma unroll
        for (int i = 0; i < 2; ++i)
            o4[o4base + i * 512 + t] = a4[i * 512 + t];
    }
}

// ---------------------------------------------------------------------------
// Fallback: plain global-atomic scatter (only if ws too small).
// ---------------------------------------------------------------------------
__global__ __launch_bounds__(256) void cic_scatter_kernel(
    const float* __restrict__ points, const float* __restrict__ values,
    float* __restrict__ out)
{
    const int tid = blockIdx.x * blockDim.x + threadIdx.x;
    if (tid >= NPTOT) return;
    const int b = tid >> 18, n = tid & (NPTS - 1);
    const float* pp = points + (size_t)tid * 3;
    const float px = (pp[0] + 0.5f) * BOX, py = (pp[1] + 0.5f) * BOX, pz = (pp[2] + 0.5f) * BOX;
    const float fx = floorf(px), fy = floorf(py), fz = floorf(pz);
    const float rx = px - fx, ry = py - fy, rz = pz - fz;
    const int ix = (int)fx, iy = (int)fy, iz = (int)fz;
    const float v0 = values[(size_t)(b * 2) * NPTS + n];
    const float v1 = values[(size_t)(b * 2 + 1) * NPTS + n];
    const float wx[2] = {1.f - rx, rx}, wy[2] = {1.f - ry, ry}, wz[2] = {1.f - rz, rz};
    float* out0 = out + (size_t)(b * 2) * VOL;
    float* out1 = out + (size_t)(b * 2 + 1) * VOL;
    for (int dz = 0; dz < 2; ++dz) {
        const int z = iz + dz; if (z >= BOX) continue;
        for (int dy = 0; dy < 2; ++dy) {
            const int y = iy + dy; if (y >= BOX) continue;
            const float wzy = wz[dz] * wy[dy];
            const int rowbase = (z * BOX + y) * BOX;
            for (int dx = 0; dx < 2; ++dx) {
                const int x = ix + dx; if (x >= BOX) continue;
                atomicAdd(out0 + rowbase + x, wzy * wx[dx] * v0);
                atomicAdd(out1 + rowbase + x, wzy * wx[dx] * v1);
            }
        }
    }
}

extern "C" void kernel_launch(void* const* d_in, const int* in_sizes, int n_in,
                              void* d_out, int out_size, void* d_ws, size_t ws_size,
                              hipStream_t stream) {
    const float* points = (const float*)d_in[0];   // [B, N, 3]
    const float* values = (const float*)d_in[1];   // [B, C, N]
    float* out = (float*)d_out;                    // [B, C, 256,256,256]

    // ws layout (16B-aligned)
    const size_t GCUR_OFF = 0;                                    // 256 u32
    const size_t OVFC_OFF = 1024;                                 // 1 u32 (+pad)
    const size_t REC1_OFF = 4096;                                 // NGRP*GCAP*16
    const size_t REC2_OFF = REC1_OFF + (size_t)NGRP * GCAP * 16;
    const size_t BST_OFF  = REC2_OFF + (size_t)NGRP * GCAP * 16;  // NBINS u32
    const size_t BCT_OFF  = BST_OFF + (size_t)NBINS * 4;
    const size_t OVF4_OFF = BCT_OFF + (size_t)NBINS * 4;          // NPTOT*16
    const size_t OVFB_OFF = OVF4_OFF + (size_t)NPTOT * 16;
    const size_t WS_NEED  = OVFB_OFF + (size_t)NPTOT * 4;

    if (ws_size < WS_NEED) {
        hipMemsetAsync(out, 0, (size_t)out_size * sizeof(float), stream);
        cic_scatter_kernel<<<NPTOT / 256, 256, 0, stream>>>(points, values, out);
        return;
    }

    char* ws = (char*)d_ws;
    unsigned* gcur     = (unsigned*)(ws + GCUR_OFF);
    unsigned* ovfcnt   = (unsigned*)(ws + OVFC_OFF);
    uint4*    rec1     = (uint4*)(ws + REC1_OFF);
    uint4*    rec2     = (uint4*)(ws + REC2_OFF);
    unsigned* binStart = (unsigned*)(ws + BST_OFF);
    unsigned* binCnt   = (unsigned*)(ws + BCT_OFF);
    uint4*    ovf4     = (uint4*)(ws + OVF4_OFF);
    unsigned* ovfbin   = (unsigned*)(ws + OVFB_OFF);

    k_zero<<<1, 512, 0, stream>>>((unsigned*)ws);     // gcur + ovfcnt
    k_l1<<<L1BLK, 256, 0, stream>>>(points, values, gcur, rec1, ovf4, ovfbin, ovfcnt);
    k_l2<<<NGRP, 512, 0, stream>>>(rec1, gcur, rec2, binStart, binCnt);
    k_region<<<NREG, 512, 0, stream>>>(rec2, binStart, binCnt, ovf4, ovfbin, ovfcnt, out);
}